// Round 16
// baseline (290.142 us; speedup 1.0000x reference)
//
#include <hip/hip_runtime.h>
#include <hip/hip_cooperative_groups.h>
#include <math.h>

namespace cg = cooperative_groups;

#define NNODES 50000
#define NEDGES 640000
#define INSZ 512
#define HID 128
#define NBLK ((NNODES + 255) / 256)   // 196

typedef short s16x8 __attribute__((ext_vector_type(8)));
typedef float f32x4 __attribute__((ext_vector_type(4)));

static __device__ inline short f2bf(float f) {
    __bf16 b = (__bf16)f;
    return __builtin_bit_cast(short, b);
}
static __device__ inline float bf2f(unsigned short u) {
    unsigned int i = (unsigned int)u << 16;
    return __builtin_bit_cast(float, i);
}

// ---------------- weight prep: both transposes in one kernel ----------------
__global__ __launch_bounds__(256) void prep_weights(const float* __restrict__ We,
                                                    const float* __restrict__ Wd,
                                                    short* __restrict__ WTe,
                                                    short* __restrict__ WTd) {
    int t = blockIdx.x * 256 + threadIdx.x;       // 131072 total
    if (t < INSZ * HID) {
        int n = t & (HID - 1);
        int k = t >> 7;
        WTe[n * INSZ + k] = f2bf(We[t]);
    } else {
        int u = t - INSZ * HID;
        int n = u & (INSZ - 1);
        int k = u >> 9;
        WTd[n * HID + k] = f2bf(Wd[u]);
    }
}

// ---------------- CSR build: single cooperative kernel, 6 phases ----------------
// zero -> count -> block-local scan -> block0 scans blocksums -> finalize -> scatter
__global__ __launch_bounds__(256) void csr_build(const int* __restrict__ erow,
                                                 const int* __restrict__ ecol,
                                                 int* __restrict__ counts,
                                                 int* __restrict__ starts,
                                                 int* __restrict__ cursor,
                                                 float* __restrict__ dinv,
                                                 int* __restrict__ csr_row,
                                                 int* __restrict__ blocksums) {
    cg::grid_group grid = cg::this_grid();
    const int t = threadIdx.x;
    const int i = blockIdx.x * 256 + t;
    const int gsz = NBLK * 256;                   // 50176

    if (i < NNODES) counts[i] = 0;
    grid.sync();

    for (int e = i; e < NEDGES; e += gsz)
        atomicAdd(&counts[ecol[e]], 1);
    grid.sync();

    __shared__ int s[256];
    const int v = (i < NNODES) ? counts[i] : 0;
    s[t] = v;
    __syncthreads();
    for (int off = 1; off < 256; off <<= 1) {
        int u = (t >= off) ? s[t - off] : 0;
        __syncthreads();
        s[t] += u;
        __syncthreads();
    }
    if (i < NNODES) {
        starts[i] = (t == 0) ? 0 : s[t - 1];      // temp: block-local exclusive
        dinv[i] = rsqrtf((float)v + 1.0f);
    }
    if (t == 255) blocksums[blockIdx.x] = s[255];
    grid.sync();

    if (blockIdx.x == 0) {
        int bv = (t < NBLK) ? blocksums[t] : 0;
        s[t] = bv;
        __syncthreads();
        for (int off = 1; off < 256; off <<= 1) {
            int u = (t >= off) ? s[t - off] : 0;
            __syncthreads();
            s[t] += u;
            __syncthreads();
        }
        if (t < NBLK) blocksums[t] = (t == 0) ? 0 : s[t - 1];   // exclusive offsets
    }
    grid.sync();

    if (i < NNODES) {
        int excl = starts[i] + blocksums[blockIdx.x];
        starts[i] = excl;
        cursor[i] = excl;
        if (i == NNODES - 1) starts[NNODES] = excl + v;
    }
    grid.sync();

    for (int e = i; e < NEDGES; e += gsz) {
        int pos = atomicAdd(&cursor[ecol[e]], 1);
        csr_row[pos] = erow[e];
    }
}

// ---------------- encoder: h = relu(x @ W_enc + b_enc), MFMA bf16 (R13, frozen) ----
#define XPAD 72
__global__ __launch_bounds__(256) void encoder_mfma(const float* __restrict__ x,
                                                    const short* __restrict__ WT,
                                                    const float* __restrict__ b,
                                                    unsigned short* __restrict__ h) {
    __shared__ short xs[2][64 * XPAD];         // 18 KB
    const int t    = threadIdx.x;
    const int lane = t & 63;
    const int wv   = t >> 6;
    const int r16  = lane & 15;
    const int kg   = lane >> 4;
    const int mbase = blockIdx.x * 64;
    const int nb    = wv * 32;

    const float4* sp[4];
    int sdst[4];
#pragma unroll
    for (int j = 0; j < 4; ++j) {
        int c = j * 256 + t;
        int row = c >> 4, c4 = c & 15;
        int gr = mbase + row; if (gr >= NNODES) gr = NNODES - 1;
        sp[j]   = (const float4*)x + (size_t)gr * (INSZ / 4) + c4;
        sdst[j] = row * XPAD + c4 * 4;
    }

    f32x4 acc[4][2] = {};
    float4 rB[4], rC[4];

    {
        float4 rA[4];
#pragma unroll
        for (int j = 0; j < 4; ++j) rA[j] = sp[j][0];
#pragma unroll
        for (int j = 0; j < 4; ++j) {
            short4 w;
            w.x = f2bf(rA[j].x); w.y = f2bf(rA[j].y);
            w.z = f2bf(rA[j].z); w.w = f2bf(rA[j].w);
            *(short4*)&xs[0][sdst[j]] = w;
        }
    }
    __syncthreads();
#pragma unroll
    for (int j = 0; j < 4; ++j) rB[j] = sp[j][16];

#pragma unroll 2
    for (int ks = 0; ks < 8; ++ks) {
        const int cur = ks & 1;
        if (ks < 6) {
#pragma unroll
            for (int j = 0; j < 4; ++j) rC[j] = sp[j][(ks + 2) * 16];
        }
#pragma unroll
        for (int kk = 0; kk < 2; ++kk) {
            s16x8 a[4], bb[2];
#pragma unroll
            for (int mt = 0; mt < 4; ++mt)
                a[mt] = *(const s16x8*)&xs[cur][(mt * 16 + r16) * XPAD + kk * 32 + kg * 8];
#pragma unroll
            for (int nt = 0; nt < 2; ++nt)
                bb[nt] = *(const s16x8*)(WT + (size_t)(nb + nt * 16 + r16) * INSZ + ks * 64 + kk * 32 + kg * 8);
#pragma unroll
            for (int mt = 0; mt < 4; ++mt)
#pragma unroll
                for (int nt = 0; nt < 2; ++nt)
                    acc[mt][nt] = __builtin_amdgcn_mfma_f32_16x16x32_bf16(a[mt], bb[nt], acc[mt][nt], 0, 0, 0);
        }
        if (ks < 7) {
#pragma unroll
            for (int j = 0; j < 4; ++j) {
                short4 w;
                w.x = f2bf(rB[j].x); w.y = f2bf(rB[j].y);
                w.z = f2bf(rB[j].z); w.w = f2bf(rB[j].w);
                *(short4*)&xs[cur ^ 1][sdst[j]] = w;
            }
#pragma unroll
            for (int j = 0; j < 4; ++j) rB[j] = rC[j];
        }
        __syncthreads();
    }

    const int ro = kg * 4;
#pragma unroll
    for (int mt = 0; mt < 4; ++mt) {
        const int row0 = mbase + mt * 16 + ro;
#pragma unroll
        for (int nt = 0; nt < 2; ++nt) {
            const int col = nb + nt * 16 + r16;
            const float bj = b[col];
#pragma unroll
            for (int v = 0; v < 4; ++v) {
                int rr = row0 + v;
                if (rr < NNODES)
                    h[(size_t)rr * HID + col] = (unsigned short)f2bf(fmaxf(acc[mt][nt][v] + bj, 0.0f));
            }
        }
    }
}

// ---------------- aggregation: half-wave (32 lanes x 4 bf16) per node, 4-way ILP ----
__global__ __launch_bounds__(256) void aggregate_csr_kernel(const int* __restrict__ starts,
                                                            const int* __restrict__ csr_row,
                                                            const float* __restrict__ dinv,
                                                            const unsigned short* __restrict__ h,
                                                            unsigned short* __restrict__ agg) {
    const int node = (blockIdx.x * 256 + threadIdx.x) >> 5;
    const int l32  = threadIdx.x & 31;
    if (node >= NNODES) return;
    const float dc = dinv[node];
    const int s0 = starts[node], s1 = starts[node + 1];
    const ushort4* hp = (const ushort4*)h;

    ushort4 sv = hp[(size_t)node * 32 + l32];
    const float sc = dc * dc;
    float4 acc;
    acc.x = bf2f(sv.x) * sc; acc.y = bf2f(sv.y) * sc;
    acc.z = bf2f(sv.z) * sc; acc.w = bf2f(sv.w) * sc;

    int i = s0;
    for (; i + 3 < s1; i += 4) {
        int r0 = csr_row[i], r1 = csr_row[i + 1], r2 = csr_row[i + 2], r3 = csr_row[i + 3];
        float n0 = dinv[r0] * dc, n1 = dinv[r1] * dc, n2 = dinv[r2] * dc, n3 = dinv[r3] * dc;
        ushort4 h0 = hp[(size_t)r0 * 32 + l32];
        ushort4 h1 = hp[(size_t)r1 * 32 + l32];
        ushort4 h2 = hp[(size_t)r2 * 32 + l32];
        ushort4 h3 = hp[(size_t)r3 * 32 + l32];
        acc.x = fmaf(n0, bf2f(h0.x), acc.x); acc.y = fmaf(n0, bf2f(h0.y), acc.y);
        acc.z = fmaf(n0, bf2f(h0.z), acc.z); acc.w = fmaf(n0, bf2f(h0.w), acc.w);
        acc.x = fmaf(n1, bf2f(h1.x), acc.x); acc.y = fmaf(n1, bf2f(h1.y), acc.y);
        acc.z = fmaf(n1, bf2f(h1.z), acc.z); acc.w = fmaf(n1, bf2f(h1.w), acc.w);
        acc.x = fmaf(n2, bf2f(h2.x), acc.x); acc.y = fmaf(n2, bf2f(h2.y), acc.y);
        acc.z = fmaf(n2, bf2f(h2.z), acc.z); acc.w = fmaf(n2, bf2f(h2.w), acc.w);
        acc.x = fmaf(n3, bf2f(h3.x), acc.x); acc.y = fmaf(n3, bf2f(h3.y), acc.y);
        acc.z = fmaf(n3, bf2f(h3.z), acc.z); acc.w = fmaf(n3, bf2f(h3.w), acc.w);
    }
    for (; i < s1; ++i) {
        int r = csr_row[i];
        float nrm = dinv[r] * dc;
        ushort4 hv = hp[(size_t)r * 32 + l32];
        acc.x = fmaf(nrm, bf2f(hv.x), acc.x); acc.y = fmaf(nrm, bf2f(hv.y), acc.y);
        acc.z = fmaf(nrm, bf2f(hv.z), acc.z); acc.w = fmaf(nrm, bf2f(hv.w), acc.w);
    }
    ushort4 ov;
    ov.x = (unsigned short)f2bf(acc.x); ov.y = (unsigned short)f2bf(acc.y);
    ov.z = (unsigned short)f2bf(acc.z); ov.w = (unsigned short)f2bf(acc.w);
    ((ushort4*)agg)[(size_t)node * 32 + l32] = ov;
}

// ---------------- decoder: out = sigmoid((agg+gb) @ W_dec + b_dec), MFMA bf16 -------
#define APAD 136   // bf16 elems per LDS A-row (128 + 8)
#define EPAD 68    // f32 per epilogue row (64 + 4)
__global__ __launch_bounds__(512) void decoder_mfma(const unsigned short* __restrict__ agg,
                                                    const float* __restrict__ gb,
                                                    const short* __restrict__ WT,
                                                    const float* __restrict__ b,
                                                    float* __restrict__ out) {
    __shared__ short as_lds[64 * APAD];        // 17.4 KB
    __shared__ float ep[8][16 * EPAD];         // 34.8 KB
    const int t    = threadIdx.x;
    const int lane = t & 63;
    const int wv   = t >> 6;
    const int r16  = lane & 15;
    const int kg   = lane >> 4;
    const int mbase = blockIdx.x * 64;
    const int nwb   = wv * 64;

    {
        const int row = t >> 3;
        const int f0  = (t & 7) * 16;
        int gr = mbase + row; if (gr >= NNODES) gr = NNODES - 1;
        const ushort4* src4 = (const ushort4*)(agg + (size_t)gr * HID + f0);
        const float4*  g4   = (const float4*)(gb + f0);
        short4* d4 = (short4*)(as_lds + row * APAD + f0);
#pragma unroll
        for (int j = 0; j < 4; ++j) {
            ushort4 u = src4[j];
            float4 g = g4[j];
            short4 w;
            w.x = f2bf(bf2f(u.x) + g.x); w.y = f2bf(bf2f(u.y) + g.y);
            w.z = f2bf(bf2f(u.z) + g.z); w.w = f2bf(bf2f(u.w) + g.w);
            d4[j] = w;
        }
    }
    __syncthreads();

    f32x4 acc[4][4] = {};
#pragma unroll
    for (int ks = 0; ks < 4; ++ks) {
        s16x8 a[4], bb[4];
#pragma unroll
        for (int mt = 0; mt < 4; ++mt)
            a[mt] = *(const s16x8*)&as_lds[(mt * 16 + r16) * APAD + ks * 32 + kg * 8];
#pragma unroll
        for (int nt = 0; nt < 4; ++nt)
            bb[nt] = *(const s16x8*)(WT + (size_t)(nwb + nt * 16 + r16) * HID + ks * 32 + kg * 8);
#pragma unroll
        for (int mt = 0; mt < 4; ++mt)
#pragma unroll
            for (int nt = 0; nt < 4; ++nt)
                acc[mt][nt] = __builtin_amdgcn_mfma_f32_16x16x32_bf16(a[mt], bb[nt], acc[mt][nt], 0, 0, 0);
    }

    float bj[4];
#pragma unroll
    for (int nt = 0; nt < 4; ++nt) bj[nt] = b[nwb + nt * 16 + r16];

    float* eps = ep[wv];
#pragma unroll
    for (int mt = 0; mt < 4; ++mt) {
#pragma unroll
        for (int nt = 0; nt < 4; ++nt)
#pragma unroll
            for (int v = 0; v < 4; ++v) {
                float z = acc[mt][nt][v] + bj[nt];
                eps[(kg * 4 + v) * EPAD + nt * 16 + r16] = 1.0f / (1.0f + __expf(-z));
            }
#pragma unroll
        for (int pass = 0; pass < 4; ++pass) {
            const int lr = pass * 4 + kg;
            float4 vv = *(const float4*)&eps[lr * EPAD + r16 * 4];
            const int rr = mbase + mt * 16 + lr;
            if (rr < NNODES)
                *(float4*)&out[(size_t)rr * INSZ + nwb + r16 * 4] = vv;
        }
    }
}

extern "C" void kernel_launch(void* const* d_in, const int* in_sizes, int n_in,
                              void* d_out, int out_size, void* d_ws, size_t ws_size,
                              hipStream_t stream) {
    const float* x        = (const float*)d_in[0];
    const float* W_enc    = (const float*)d_in[1];
    const float* b_enc    = (const float*)d_in[2];
    const float* W_dec    = (const float*)d_in[3];
    const float* b_dec    = (const float*)d_in[4];
    const float* gcn_bias = (const float*)d_in[5];
    const int*   edge     = (const int*)d_in[6];
    const int*   erow = edge;
    const int*   ecol = edge + NEDGES;

    float* out = (float*)d_out;
    // ws: agg bf16 + dinv + wdecT (R13 layout)
    unsigned short* agg = (unsigned short*)d_ws;
    float* dinv  = (float*)(agg + (size_t)NNODES * HID);
    short* wdecT = (short*)(dinv + NNODES);
    // d_out tail scratch (dead before decoder writes d_out):
    unsigned short* h = (unsigned short*)out;
    int*   csr_row   = (int*)(out + (size_t)NNODES * HID);
    int*   starts    = csr_row + NEDGES;
    int*   counts    = starts + NNODES + 1;
    int*   cursor    = counts + NNODES;
    int*   blocksums = cursor + NNODES;
    short* wencT     = (short*)(blocksums + 256);

    prep_weights<<<(2 * INSZ * HID + 255) / 256, 256, 0, stream>>>(W_enc, W_dec, wencT, wdecT);

    int*   counts_a = counts;  int* starts_a = starts;  int* cursor_a = cursor;
    float* dinv_a = dinv;      int* csr_a = csr_row;    int* bs_a = blocksums;
    const int* erow_a = erow;  const int* ecol_a = ecol;
    void* args[] = {(void*)&erow_a, (void*)&ecol_a, (void*)&counts_a, (void*)&starts_a,
                    (void*)&cursor_a, (void*)&dinv_a, (void*)&csr_a, (void*)&bs_a};
    hipLaunchCooperativeKernel((void*)csr_build, dim3(NBLK), dim3(256), args, 0, stream);

    encoder_mfma<<<(NNODES + 63) / 64, 256, 0, stream>>>(x, wencT, b_enc, h);
    aggregate_csr_kernel<<<((size_t)NNODES * 32 + 255) / 256, 256, 0, stream>>>(starts, csr_row, dinv, h, agg);
    decoder_mfma<<<(NNODES + 63) / 64, 512, 0, stream>>>(agg, gcn_bias, wdecT, b_dec, out);
}

// Round 17
// 188.196 us; speedup vs baseline: 1.5417x; 1.5417x over previous
//
#include <hip/hip_runtime.h>
#include <math.h>

#define NNODES 50000
#define NEDGES 640000
#define INSZ 512
#define HID 128
#define NBLK ((NNODES + 255) / 256)   // 196

typedef short s16x8 __attribute__((ext_vector_type(8)));
typedef float f32x4 __attribute__((ext_vector_type(4)));

static __device__ inline short f2bf(float f) {
    __bf16 b = (__bf16)f;
    return __builtin_bit_cast(short, b);
}
static __device__ inline float bf2f(unsigned short u) {
    unsigned int i = (unsigned int)u << 16;
    return __builtin_bit_cast(float, i);
}

// ---------------- weight prep: both transposes in one kernel ----------------
__global__ __launch_bounds__(256) void prep_weights(const float* __restrict__ We,
                                                    const float* __restrict__ Wd,
                                                    short* __restrict__ WTe,
                                                    short* __restrict__ WTd) {
    int t = blockIdx.x * 256 + threadIdx.x;       // 131072 total
    if (t < INSZ * HID) {
        int n = t & (HID - 1);
        int k = t >> 7;
        WTe[n * INSZ + k] = f2bf(We[t]);
    } else {
        int u = t - INSZ * HID;
        int n = u & (INSZ - 1);
        int k = u >> 9;
        WTd[n * HID + k] = f2bf(Wd[u]);
    }
}

// ---------------- CSR build (R13 split chain, proper grid sizes) ----------------
__global__ __launch_bounds__(256) void count_kernel(const int* __restrict__ col,
                                                    int* __restrict__ counts) {
    int e = blockIdx.x * blockDim.x + threadIdx.x;
    if (e < NEDGES) atomicAdd(&counts[col[e]], 1);
}

__global__ __launch_bounds__(256) void partial_kernel(const int* __restrict__ counts,
                                                      int* __restrict__ blocksums) {
    int i = blockIdx.x * 256 + threadIdx.x;
    int v = (i < NNODES) ? counts[i] : 0;
#pragma unroll
    for (int off = 32; off; off >>= 1) v += __shfl_down(v, off, 64);
    __shared__ int ws[4];
    if ((threadIdx.x & 63) == 0) ws[threadIdx.x >> 6] = v;
    __syncthreads();
    if (threadIdx.x == 0) blocksums[blockIdx.x] = ws[0] + ws[1] + ws[2] + ws[3];
}

__global__ __launch_bounds__(256) void scan_blocks(const int* __restrict__ blocksums,
                                                   int* __restrict__ blockoffs) {
    __shared__ int s[256];
    const int t = threadIdx.x;
    s[t] = (t < NBLK) ? blocksums[t] : 0;
    __syncthreads();
    for (int off = 1; off < 256; off <<= 1) {
        int u = (t >= off) ? s[t - off] : 0;
        __syncthreads();
        s[t] += u;
        __syncthreads();
    }
    blockoffs[t] = (t == 0) ? 0 : s[t - 1];
}

__global__ __launch_bounds__(256) void scan_final(const int* __restrict__ counts,
                                                  const int* __restrict__ blockoffs,
                                                  int* __restrict__ starts,
                                                  int* __restrict__ cursor,
                                                  float* __restrict__ dinv) {
    __shared__ int s[256];
    const int t = threadIdx.x;
    const int i = blockIdx.x * 256 + t;
    int v = (i < NNODES) ? counts[i] : 0;
    s[t] = v;
    __syncthreads();
    for (int off = 1; off < 256; off <<= 1) {
        int u = (t >= off) ? s[t - off] : 0;
        __syncthreads();
        s[t] += u;
        __syncthreads();
    }
    int excl = ((t == 0) ? 0 : s[t - 1]) + blockoffs[blockIdx.x];
    if (i < NNODES) {
        starts[i] = excl;
        cursor[i] = excl;
        dinv[i] = rsqrtf((float)v + 1.0f);
        if (i == NNODES - 1) starts[NNODES] = excl + v;
    }
}

__global__ __launch_bounds__(256) void scatter_kernel(const int* __restrict__ erow,
                                                      const int* __restrict__ ecol,
                                                      int* __restrict__ cursor,
                                                      int* __restrict__ csr_row) {
    int e = blockIdx.x * blockDim.x + threadIdx.x;
    if (e < NEDGES) {
        int pos = atomicAdd(&cursor[ecol[e]], 1);
        csr_row[pos] = erow[e];
    }
}

// ---------------- encoder: h = relu(x @ W_enc + b_enc), MFMA bf16 (R13, frozen) ----
#define XPAD 72
__global__ __launch_bounds__(256) void encoder_mfma(const float* __restrict__ x,
                                                    const short* __restrict__ WT,
                                                    const float* __restrict__ b,
                                                    unsigned short* __restrict__ h) {
    __shared__ short xs[2][64 * XPAD];         // 18 KB
    const int t    = threadIdx.x;
    const int lane = t & 63;
    const int wv   = t >> 6;
    const int r16  = lane & 15;
    const int kg   = lane >> 4;
    const int mbase = blockIdx.x * 64;
    const int nb    = wv * 32;

    const float4* sp[4];
    int sdst[4];
#pragma unroll
    for (int j = 0; j < 4; ++j) {
        int c = j * 256 + t;
        int row = c >> 4, c4 = c & 15;
        int gr = mbase + row; if (gr >= NNODES) gr = NNODES - 1;
        sp[j]   = (const float4*)x + (size_t)gr * (INSZ / 4) + c4;
        sdst[j] = row * XPAD + c4 * 4;
    }

    f32x4 acc[4][2] = {};
    float4 rB[4], rC[4];

    {
        float4 rA[4];
#pragma unroll
        for (int j = 0; j < 4; ++j) rA[j] = sp[j][0];
#pragma unroll
        for (int j = 0; j < 4; ++j) {
            short4 w;
            w.x = f2bf(rA[j].x); w.y = f2bf(rA[j].y);
            w.z = f2bf(rA[j].z); w.w = f2bf(rA[j].w);
            *(short4*)&xs[0][sdst[j]] = w;
        }
    }
    __syncthreads();
#pragma unroll
    for (int j = 0; j < 4; ++j) rB[j] = sp[j][16];

#pragma unroll 2
    for (int ks = 0; ks < 8; ++ks) {
        const int cur = ks & 1;
        if (ks < 6) {
#pragma unroll
            for (int j = 0; j < 4; ++j) rC[j] = sp[j][(ks + 2) * 16];
        }
#pragma unroll
        for (int kk = 0; kk < 2; ++kk) {
            s16x8 a[4], bb[2];
#pragma unroll
            for (int mt = 0; mt < 4; ++mt)
                a[mt] = *(const s16x8*)&xs[cur][(mt * 16 + r16) * XPAD + kk * 32 + kg * 8];
#pragma unroll
            for (int nt = 0; nt < 2; ++nt)
                bb[nt] = *(const s16x8*)(WT + (size_t)(nb + nt * 16 + r16) * INSZ + ks * 64 + kk * 32 + kg * 8);
#pragma unroll
            for (int mt = 0; mt < 4; ++mt)
#pragma unroll
                for (int nt = 0; nt < 2; ++nt)
                    acc[mt][nt] = __builtin_amdgcn_mfma_f32_16x16x32_bf16(a[mt], bb[nt], acc[mt][nt], 0, 0, 0);
        }
        if (ks < 7) {
#pragma unroll
            for (int j = 0; j < 4; ++j) {
                short4 w;
                w.x = f2bf(rB[j].x); w.y = f2bf(rB[j].y);
                w.z = f2bf(rB[j].z); w.w = f2bf(rB[j].w);
                *(short4*)&xs[cur ^ 1][sdst[j]] = w;
            }
#pragma unroll
            for (int j = 0; j < 4; ++j) rB[j] = rC[j];
        }
        __syncthreads();
    }

    const int ro = kg * 4;
#pragma unroll
    for (int mt = 0; mt < 4; ++mt) {
        const int row0 = mbase + mt * 16 + ro;
#pragma unroll
        for (int nt = 0; nt < 2; ++nt) {
            const int col = nb + nt * 16 + r16;
            const float bj = b[col];
#pragma unroll
            for (int v = 0; v < 4; ++v) {
                int rr = row0 + v;
                if (rr < NNODES)
                    h[(size_t)rr * HID + col] = (unsigned short)f2bf(fmaxf(acc[mt][nt][v] + bj, 0.0f));
            }
        }
    }
}

// ---------------- aggregation: half-wave (32 lanes x 4 bf16) per node, 4-way ILP ----
__global__ __launch_bounds__(256) void aggregate_csr_kernel(const int* __restrict__ starts,
                                                            const int* __restrict__ csr_row,
                                                            const float* __restrict__ dinv,
                                                            const unsigned short* __restrict__ h,
                                                            unsigned short* __restrict__ agg) {
    const int node = (blockIdx.x * 256 + threadIdx.x) >> 5;
    const int l32  = threadIdx.x & 31;
    if (node >= NNODES) return;
    const float dc = dinv[node];
    const int s0 = starts[node], s1 = starts[node + 1];
    const ushort4* hp = (const ushort4*)h;

    ushort4 sv = hp[(size_t)node * 32 + l32];
    const float sc = dc * dc;
    float4 acc;
    acc.x = bf2f(sv.x) * sc; acc.y = bf2f(sv.y) * sc;
    acc.z = bf2f(sv.z) * sc; acc.w = bf2f(sv.w) * sc;

    int i = s0;
    for (; i + 3 < s1; i += 4) {
        int r0 = csr_row[i], r1 = csr_row[i + 1], r2 = csr_row[i + 2], r3 = csr_row[i + 3];
        float n0 = dinv[r0] * dc, n1 = dinv[r1] * dc, n2 = dinv[r2] * dc, n3 = dinv[r3] * dc;
        ushort4 h0 = hp[(size_t)r0 * 32 + l32];
        ushort4 h1 = hp[(size_t)r1 * 32 + l32];
        ushort4 h2 = hp[(size_t)r2 * 32 + l32];
        ushort4 h3 = hp[(size_t)r3 * 32 + l32];
        acc.x = fmaf(n0, bf2f(h0.x), acc.x); acc.y = fmaf(n0, bf2f(h0.y), acc.y);
        acc.z = fmaf(n0, bf2f(h0.z), acc.z); acc.w = fmaf(n0, bf2f(h0.w), acc.w);
        acc.x = fmaf(n1, bf2f(h1.x), acc.x); acc.y = fmaf(n1, bf2f(h1.y), acc.y);
        acc.z = fmaf(n1, bf2f(h1.z), acc.z); acc.w = fmaf(n1, bf2f(h1.w), acc.w);
        acc.x = fmaf(n2, bf2f(h2.x), acc.x); acc.y = fmaf(n2, bf2f(h2.y), acc.y);
        acc.z = fmaf(n2, bf2f(h2.z), acc.z); acc.w = fmaf(n2, bf2f(h2.w), acc.w);
        acc.x = fmaf(n3, bf2f(h3.x), acc.x); acc.y = fmaf(n3, bf2f(h3.y), acc.y);
        acc.z = fmaf(n3, bf2f(h3.z), acc.z); acc.w = fmaf(n3, bf2f(h3.w), acc.w);
    }
    for (; i < s1; ++i) {
        int r = csr_row[i];
        float nrm = dinv[r] * dc;
        ushort4 hv = hp[(size_t)r * 32 + l32];
        acc.x = fmaf(nrm, bf2f(hv.x), acc.x); acc.y = fmaf(nrm, bf2f(hv.y), acc.y);
        acc.z = fmaf(nrm, bf2f(hv.z), acc.z); acc.w = fmaf(nrm, bf2f(hv.w), acc.w);
    }
    ushort4 ov;
    ov.x = (unsigned short)f2bf(acc.x); ov.y = (unsigned short)f2bf(acc.y);
    ov.z = (unsigned short)f2bf(acc.z); ov.w = (unsigned short)f2bf(acc.w);
    ((ushort4*)agg)[(size_t)node * 32 + l32] = ov;
}

// ---------------- decoder: out = sigmoid((agg+gb) @ W_dec + b_dec), MFMA bf16 -------
#define APAD 136   // bf16 elems per LDS A-row (128 + 8)
#define EPAD 68    // f32 per epilogue row (64 + 4)
__global__ __launch_bounds__(512) void decoder_mfma(const unsigned short* __restrict__ agg,
                                                    const float* __restrict__ gb,
                                                    const short* __restrict__ WT,
                                                    const float* __restrict__ b,
                                                    float* __restrict__ out) {
    __shared__ short as_lds[64 * APAD];        // 17.4 KB
    __shared__ float ep[8][16 * EPAD];         // 34.8 KB
    const int t    = threadIdx.x;
    const int lane = t & 63;
    const int wv   = t >> 6;
    const int r16  = lane & 15;
    const int kg   = lane >> 4;
    const int mbase = blockIdx.x * 64;
    const int nwb   = wv * 64;

    {
        const int row = t >> 3;
        const int f0  = (t & 7) * 16;
        int gr = mbase + row; if (gr >= NNODES) gr = NNODES - 1;
        const ushort4* src4 = (const ushort4*)(agg + (size_t)gr * HID + f0);
        const float4*  g4   = (const float4*)(gb + f0);
        short4* d4 = (short4*)(as_lds + row * APAD + f0);
#pragma unroll
        for (int j = 0; j < 4; ++j) {
            ushort4 u = src4[j];
            float4 g = g4[j];
            short4 w;
            w.x = f2bf(bf2f(u.x) + g.x); w.y = f2bf(bf2f(u.y) + g.y);
            w.z = f2bf(bf2f(u.z) + g.z); w.w = f2bf(bf2f(u.w) + g.w);
            d4[j] = w;
        }
    }
    __syncthreads();

    f32x4 acc[4][4] = {};
#pragma unroll
    for (int ks = 0; ks < 4; ++ks) {
        s16x8 a[4], bb[4];
#pragma unroll
        for (int mt = 0; mt < 4; ++mt)
            a[mt] = *(const s16x8*)&as_lds[(mt * 16 + r16) * APAD + ks * 32 + kg * 8];
#pragma unroll
        for (int nt = 0; nt < 4; ++nt)
            bb[nt] = *(const s16x8*)(WT + (size_t)(nwb + nt * 16 + r16) * HID + ks * 32 + kg * 8);
#pragma unroll
        for (int mt = 0; mt < 4; ++mt)
#pragma unroll
            for (int nt = 0; nt < 4; ++nt)
                acc[mt][nt] = __builtin_amdgcn_mfma_f32_16x16x32_bf16(a[mt], bb[nt], acc[mt][nt], 0, 0, 0);
    }

    float bj[4];
#pragma unroll
    for (int nt = 0; nt < 4; ++nt) bj[nt] = b[nwb + nt * 16 + r16];

    float* eps = ep[wv];
#pragma unroll
    for (int mt = 0; mt < 4; ++mt) {
#pragma unroll
        for (int nt = 0; nt < 4; ++nt)
#pragma unroll
            for (int v = 0; v < 4; ++v) {
                float z = acc[mt][nt][v] + bj[nt];
                eps[(kg * 4 + v) * EPAD + nt * 16 + r16] = 1.0f / (1.0f + __expf(-z));
            }
#pragma unroll
        for (int pass = 0; pass < 4; ++pass) {
            const int lr = pass * 4 + kg;
            float4 vv = *(const float4*)&eps[lr * EPAD + r16 * 4];
            const int rr = mbase + mt * 16 + lr;
            if (rr < NNODES)
                *(float4*)&out[(size_t)rr * INSZ + nwb + r16 * 4] = vv;
        }
    }
}

extern "C" void kernel_launch(void* const* d_in, const int* in_sizes, int n_in,
                              void* d_out, int out_size, void* d_ws, size_t ws_size,
                              hipStream_t stream) {
    const float* x        = (const float*)d_in[0];
    const float* W_enc    = (const float*)d_in[1];
    const float* b_enc    = (const float*)d_in[2];
    const float* W_dec    = (const float*)d_in[3];
    const float* b_dec    = (const float*)d_in[4];
    const float* gcn_bias = (const float*)d_in[5];
    const int*   edge     = (const int*)d_in[6];
    const int*   erow = edge;
    const int*   ecol = edge + NEDGES;

    float* out = (float*)d_out;
    // ws: agg bf16 + dinv + wdecT (R13 layout)
    unsigned short* agg = (unsigned short*)d_ws;
    float* dinv  = (float*)(agg + (size_t)NNODES * HID);
    short* wdecT = (short*)(dinv + NNODES);
    // d_out tail scratch (dead before decoder writes d_out):
    unsigned short* h = (unsigned short*)out;
    int*   csr_row   = (int*)(out + (size_t)NNODES * HID);
    int*   starts    = csr_row + NEDGES;
    int*   counts    = starts + NNODES + 1;
    int*   cursor    = counts + NNODES;
    int*   blocksums = cursor + NNODES;
    int*   blockoffs = blocksums + 256;
    short* wencT     = (short*)(blockoffs + 256);

    hipMemsetAsync(counts, 0, (size_t)NNODES * sizeof(int), stream);
    prep_weights<<<(2 * INSZ * HID + 255) / 256, 256, 0, stream>>>(W_enc, W_dec, wencT, wdecT);
    count_kernel<<<(NEDGES + 255) / 256, 256, 0, stream>>>(ecol, counts);
    partial_kernel<<<NBLK, 256, 0, stream>>>(counts, blocksums);
    scan_blocks<<<1, 256, 0, stream>>>(blocksums, blockoffs);
    scan_final<<<NBLK, 256, 0, stream>>>(counts, blockoffs, starts, cursor, dinv);
    scatter_kernel<<<(NEDGES + 255) / 256, 256, 0, stream>>>(erow, ecol, cursor, csr_row);
    encoder_mfma<<<(NNODES + 63) / 64, 256, 0, stream>>>(x, wencT, b_enc, h);
    aggregate_csr_kernel<<<((size_t)NNODES * 32 + 255) / 256, 256, 0, stream>>>(starts, csr_row, dinv, h, agg);
    decoder_mfma<<<(NNODES + 63) / 64, 512, 0, stream>>>(agg, gcn_bias, wdecT, b_dec, out);
}

// Round 18
// 187.176 us; speedup vs baseline: 1.5501x; 1.0054x over previous
//
#include <hip/hip_runtime.h>
#include <math.h>

#define NNODES 50000
#define NEDGES 640000
#define INSZ 512
#define HID 128
#define NBLK ((NNODES + 255) / 256)   // 196

typedef short s16x8 __attribute__((ext_vector_type(8)));
typedef float f32x4 __attribute__((ext_vector_type(4)));

static __device__ inline short f2bf(float f) {
    __bf16 b = (__bf16)f;
    return __builtin_bit_cast(short, b);
}
static __device__ inline float bf2f(unsigned short u) {
    unsigned int i = (unsigned int)u << 16;
    return __builtin_bit_cast(float, i);
}

// ---------------- weight prep: both transposes in one kernel ----------------
__global__ __launch_bounds__(256) void prep_weights(const float* __restrict__ We,
                                                    const float* __restrict__ Wd,
                                                    short* __restrict__ WTe,
                                                    short* __restrict__ WTd) {
    int t = blockIdx.x * 256 + threadIdx.x;       // 131072 total
    if (t < INSZ * HID) {
        int n = t & (HID - 1);
        int k = t >> 7;
        WTe[n * INSZ + k] = f2bf(We[t]);
    } else {
        int u = t - INSZ * HID;
        int n = u & (INSZ - 1);
        int k = u >> 9;
        WTd[n * HID + k] = f2bf(Wd[u]);
    }
}

// ---------------- CSR build (split chain, proper grid sizes) ----------------
__global__ __launch_bounds__(256) void count_kernel(const int* __restrict__ col,
                                                    int* __restrict__ counts) {
    int e = blockIdx.x * blockDim.x + threadIdx.x;
    if (e < NEDGES) atomicAdd(&counts[col[e]], 1);
}

__global__ __launch_bounds__(256) void partial_kernel(const int* __restrict__ counts,
                                                      int* __restrict__ blocksums) {
    int i = blockIdx.x * 256 + threadIdx.x;
    int v = (i < NNODES) ? counts[i] : 0;
#pragma unroll
    for (int off = 32; off; off >>= 1) v += __shfl_down(v, off, 64);
    __shared__ int ws[4];
    if ((threadIdx.x & 63) == 0) ws[threadIdx.x >> 6] = v;
    __syncthreads();
    if (threadIdx.x == 0) blocksums[blockIdx.x] = ws[0] + ws[1] + ws[2] + ws[3];
}

__global__ __launch_bounds__(256) void scan_blocks(const int* __restrict__ blocksums,
                                                   int* __restrict__ blockoffs) {
    __shared__ int s[256];
    const int t = threadIdx.x;
    s[t] = (t < NBLK) ? blocksums[t] : 0;
    __syncthreads();
    for (int off = 1; off < 256; off <<= 1) {
        int u = (t >= off) ? s[t - off] : 0;
        __syncthreads();
        s[t] += u;
        __syncthreads();
    }
    blockoffs[t] = (t == 0) ? 0 : s[t - 1];
}

__global__ __launch_bounds__(256) void scan_final(const int* __restrict__ counts,
                                                  const int* __restrict__ blockoffs,
                                                  int* __restrict__ starts,
                                                  int* __restrict__ cursor,
                                                  float* __restrict__ dinv) {
    __shared__ int s[256];
    const int t = threadIdx.x;
    const int i = blockIdx.x * 256 + t;
    int v = (i < NNODES) ? counts[i] : 0;
    s[t] = v;
    __syncthreads();
    for (int off = 1; off < 256; off <<= 1) {
        int u = (t >= off) ? s[t - off] : 0;
        __syncthreads();
        s[t] += u;
        __syncthreads();
    }
    int excl = ((t == 0) ? 0 : s[t - 1]) + blockoffs[blockIdx.x];
    if (i < NNODES) {
        starts[i] = excl;
        cursor[i] = excl;
        dinv[i] = rsqrtf((float)v + 1.0f);
        if (i == NNODES - 1) starts[NNODES] = excl + v;
    }
}

__global__ __launch_bounds__(256) void scatter_kernel(const int* __restrict__ erow,
                                                      const int* __restrict__ ecol,
                                                      int* __restrict__ cursor,
                                                      int* __restrict__ csr_row) {
    int e = blockIdx.x * blockDim.x + threadIdx.x;
    if (e < NEDGES) {
        int pos = atomicAdd(&cursor[ecol[e]], 1);
        csr_row[pos] = erow[e];
    }
}

// ---------------- encoder: h = relu(x @ W_enc + b_enc), MFMA bf16 (frozen) ----
#define XPAD 72
__global__ __launch_bounds__(256) void encoder_mfma(const float* __restrict__ x,
                                                    const short* __restrict__ WT,
                                                    const float* __restrict__ b,
                                                    unsigned short* __restrict__ h) {
    __shared__ short xs[2][64 * XPAD];         // 18 KB
    const int t    = threadIdx.x;
    const int lane = t & 63;
    const int wv   = t >> 6;
    const int r16  = lane & 15;
    const int kg   = lane >> 4;
    const int mbase = blockIdx.x * 64;
    const int nb    = wv * 32;

    const float4* sp[4];
    int sdst[4];
#pragma unroll
    for (int j = 0; j < 4; ++j) {
        int c = j * 256 + t;
        int row = c >> 4, c4 = c & 15;
        int gr = mbase + row; if (gr >= NNODES) gr = NNODES - 1;
        sp[j]   = (const float4*)x + (size_t)gr * (INSZ / 4) + c4;
        sdst[j] = row * XPAD + c4 * 4;
    }

    f32x4 acc[4][2] = {};
    float4 rB[4], rC[4];

    {
        float4 rA[4];
#pragma unroll
        for (int j = 0; j < 4; ++j) rA[j] = sp[j][0];
#pragma unroll
        for (int j = 0; j < 4; ++j) {
            short4 w;
            w.x = f2bf(rA[j].x); w.y = f2bf(rA[j].y);
            w.z = f2bf(rA[j].z); w.w = f2bf(rA[j].w);
            *(short4*)&xs[0][sdst[j]] = w;
        }
    }
    __syncthreads();
#pragma unroll
    for (int j = 0; j < 4; ++j) rB[j] = sp[j][16];

#pragma unroll 2
    for (int ks = 0; ks < 8; ++ks) {
        const int cur = ks & 1;
        if (ks < 6) {
#pragma unroll
            for (int j = 0; j < 4; ++j) rC[j] = sp[j][(ks + 2) * 16];
        }
#pragma unroll
        for (int kk = 0; kk < 2; ++kk) {
            s16x8 a[4], bb[2];
#pragma unroll
            for (int mt = 0; mt < 4; ++mt)
                a[mt] = *(const s16x8*)&xs[cur][(mt * 16 + r16) * XPAD + kk * 32 + kg * 8];
#pragma unroll
            for (int nt = 0; nt < 2; ++nt)
                bb[nt] = *(const s16x8*)(WT + (size_t)(nb + nt * 16 + r16) * INSZ + ks * 64 + kk * 32 + kg * 8);
#pragma unroll
            for (int mt = 0; mt < 4; ++mt)
#pragma unroll
                for (int nt = 0; nt < 2; ++nt)
                    acc[mt][nt] = __builtin_amdgcn_mfma_f32_16x16x32_bf16(a[mt], bb[nt], acc[mt][nt], 0, 0, 0);
        }
        if (ks < 7) {
#pragma unroll
            for (int j = 0; j < 4; ++j) {
                short4 w;
                w.x = f2bf(rB[j].x); w.y = f2bf(rB[j].y);
                w.z = f2bf(rB[j].z); w.w = f2bf(rB[j].w);
                *(short4*)&xs[cur ^ 1][sdst[j]] = w;
            }
#pragma unroll
            for (int j = 0; j < 4; ++j) rB[j] = rC[j];
        }
        __syncthreads();
    }

    const int ro = kg * 4;
#pragma unroll
    for (int mt = 0; mt < 4; ++mt) {
        const int row0 = mbase + mt * 16 + ro;
#pragma unroll
        for (int nt = 0; nt < 2; ++nt) {
            const int col = nb + nt * 16 + r16;
            const float bj = b[col];
#pragma unroll
            for (int v = 0; v < 4; ++v) {
                int rr = row0 + v;
                if (rr < NNODES)
                    h[(size_t)rr * HID + col] = (unsigned short)f2bf(fmaxf(acc[mt][nt][v] + bj, 0.0f));
            }
        }
    }
}

// ---------------- aggregation: half-wave (32 lanes x 4 bf16) per node, 8-way ILP ----
__global__ __launch_bounds__(256) void aggregate_csr_kernel(const int* __restrict__ starts,
                                                            const int* __restrict__ csr_row,
                                                            const float* __restrict__ dinv,
                                                            const unsigned short* __restrict__ h,
                                                            unsigned short* __restrict__ agg) {
    const int node = (blockIdx.x * 256 + threadIdx.x) >> 5;
    const int l32  = threadIdx.x & 31;
    if (node >= NNODES) return;
    const float dc = dinv[node];
    const int s0 = starts[node], s1 = starts[node + 1];
    const ushort4* hp = (const ushort4*)h;

    ushort4 sv = hp[(size_t)node * 32 + l32];
    const float sc = dc * dc;
    float4 acc;
    acc.x = bf2f(sv.x) * sc; acc.y = bf2f(sv.y) * sc;
    acc.z = bf2f(sv.z) * sc; acc.w = bf2f(sv.w) * sc;

    int i = s0;
    for (; i + 7 < s1; i += 8) {
        int r[8]; float nn[8]; ushort4 hv[8];
#pragma unroll
        for (int j = 0; j < 8; ++j) r[j] = csr_row[i + j];
#pragma unroll
        for (int j = 0; j < 8; ++j) hv[j] = hp[(size_t)r[j] * 32 + l32];
#pragma unroll
        for (int j = 0; j < 8; ++j) nn[j] = dinv[r[j]] * dc;
#pragma unroll
        for (int j = 0; j < 8; ++j) {
            acc.x = fmaf(nn[j], bf2f(hv[j].x), acc.x);
            acc.y = fmaf(nn[j], bf2f(hv[j].y), acc.y);
            acc.z = fmaf(nn[j], bf2f(hv[j].z), acc.z);
            acc.w = fmaf(nn[j], bf2f(hv[j].w), acc.w);
        }
    }
    for (; i + 3 < s1; i += 4) {
        int r[4]; float nn[4]; ushort4 hv[4];
#pragma unroll
        for (int j = 0; j < 4; ++j) r[j] = csr_row[i + j];
#pragma unroll
        for (int j = 0; j < 4; ++j) hv[j] = hp[(size_t)r[j] * 32 + l32];
#pragma unroll
        for (int j = 0; j < 4; ++j) nn[j] = dinv[r[j]] * dc;
#pragma unroll
        for (int j = 0; j < 4; ++j) {
            acc.x = fmaf(nn[j], bf2f(hv[j].x), acc.x);
            acc.y = fmaf(nn[j], bf2f(hv[j].y), acc.y);
            acc.z = fmaf(nn[j], bf2f(hv[j].z), acc.z);
            acc.w = fmaf(nn[j], bf2f(hv[j].w), acc.w);
        }
    }
    for (; i < s1; ++i) {
        int r = csr_row[i];
        float nrm = dinv[r] * dc;
        ushort4 hv = hp[(size_t)r * 32 + l32];
        acc.x = fmaf(nrm, bf2f(hv.x), acc.x); acc.y = fmaf(nrm, bf2f(hv.y), acc.y);
        acc.z = fmaf(nrm, bf2f(hv.z), acc.z); acc.w = fmaf(nrm, bf2f(hv.w), acc.w);
    }
    ushort4 ov;
    ov.x = (unsigned short)f2bf(acc.x); ov.y = (unsigned short)f2bf(acc.y);
    ov.z = (unsigned short)f2bf(acc.z); ov.w = (unsigned short)f2bf(acc.w);
    ((ushort4*)agg)[(size_t)node * 32 + l32] = ov;
}

// ---------------- decoder: out = sigmoid((agg+gb) @ W_dec + b_dec), MFMA bf16 -------
// Epilogue LDS halved (2 n-tiles per pass): total LDS 35.8 KB -> 3 blocks/CU.
#define APAD 136   // bf16 elems per LDS A-row (128 + 8)
#define EP2  36    // f32 per epilogue row (32 + 4)
__global__ __launch_bounds__(512) void decoder_mfma(const unsigned short* __restrict__ agg,
                                                    const float* __restrict__ gb,
                                                    const short* __restrict__ WT,
                                                    const float* __restrict__ b,
                                                    float* __restrict__ out) {
    __shared__ short as_lds[64 * APAD];        // 17.4 KB
    __shared__ float ep[8][16 * EP2];          // 18.4 KB
    const int t    = threadIdx.x;
    const int lane = t & 63;
    const int wv   = t >> 6;
    const int r16  = lane & 15;
    const int kg   = lane >> 4;
    const int l8   = lane & 7;
    const int lr8  = lane >> 3;                // 0..7
    const int mbase = blockIdx.x * 64;
    const int nwb   = wv * 64;

    {
        const int row = t >> 3;
        const int f0  = (t & 7) * 16;
        int gr = mbase + row; if (gr >= NNODES) gr = NNODES - 1;
        const ushort4* src4 = (const ushort4*)(agg + (size_t)gr * HID + f0);
        const float4*  g4   = (const float4*)(gb + f0);
        short4* d4 = (short4*)(as_lds + row * APAD + f0);
#pragma unroll
        for (int j = 0; j < 4; ++j) {
            ushort4 u = src4[j];
            float4 g = g4[j];
            short4 w;
            w.x = f2bf(bf2f(u.x) + g.x); w.y = f2bf(bf2f(u.y) + g.y);
            w.z = f2bf(bf2f(u.z) + g.z); w.w = f2bf(bf2f(u.w) + g.w);
            d4[j] = w;
        }
    }
    __syncthreads();

    f32x4 acc[4][4] = {};
#pragma unroll
    for (int ks = 0; ks < 4; ++ks) {
        s16x8 a[4], bb[4];
#pragma unroll
        for (int mt = 0; mt < 4; ++mt)
            a[mt] = *(const s16x8*)&as_lds[(mt * 16 + r16) * APAD + ks * 32 + kg * 8];
#pragma unroll
        for (int nt = 0; nt < 4; ++nt)
            bb[nt] = *(const s16x8*)(WT + (size_t)(nwb + nt * 16 + r16) * HID + ks * 32 + kg * 8);
#pragma unroll
        for (int mt = 0; mt < 4; ++mt)
#pragma unroll
            for (int nt = 0; nt < 4; ++nt)
                acc[mt][nt] = __builtin_amdgcn_mfma_f32_16x16x32_bf16(a[mt], bb[nt], acc[mt][nt], 0, 0, 0);
    }

    float bj[4];
#pragma unroll
    for (int nt = 0; nt < 4; ++nt) bj[nt] = b[nwb + nt * 16 + r16];

    float* eps = ep[wv];
#pragma unroll
    for (int mt = 0; mt < 4; ++mt) {
#pragma unroll
        for (int half = 0; half < 2; ++half) {
#pragma unroll
            for (int ntl = 0; ntl < 2; ++ntl) {
                const int nt = half * 2 + ntl;
#pragma unroll
                for (int v = 0; v < 4; ++v) {
                    float z = acc[mt][nt][v] + bj[nt];
                    eps[(kg * 4 + v) * EP2 + ntl * 16 + r16] = 1.0f / (1.0f + __expf(-z));
                }
            }
            // store 16 rows x 32 cols: 2 passes of 8 rows, 128B contiguous per row
#pragma unroll
            for (int p = 0; p < 2; ++p) {
                const int row = p * 8 + lr8;
                float4 vv = *(const float4*)&eps[row * EP2 + l8 * 4];
                const int rr = mbase + mt * 16 + row;
                if (rr < NNODES)
                    *(float4*)&out[(size_t)rr * INSZ + nwb + half * 32 + l8 * 4] = vv;
            }
        }
    }
}

extern "C" void kernel_launch(void* const* d_in, const int* in_sizes, int n_in,
                              void* d_out, int out_size, void* d_ws, size_t ws_size,
                              hipStream_t stream) {
    const float* x        = (const float*)d_in[0];
    const float* W_enc    = (const float*)d_in[1];
    const float* b_enc    = (const float*)d_in[2];
    const float* W_dec    = (const float*)d_in[3];
    const float* b_dec    = (const float*)d_in[4];
    const float* gcn_bias = (const float*)d_in[5];
    const int*   edge     = (const int*)d_in[6];
    const int*   erow = edge;
    const int*   ecol = edge + NEDGES;

    float* out = (float*)d_out;
    unsigned short* agg = (unsigned short*)d_ws;
    float* dinv  = (float*)(agg + (size_t)NNODES * HID);
    short* wdecT = (short*)(dinv + NNODES);
    unsigned short* h = (unsigned short*)out;
    int*   csr_row   = (int*)(out + (size_t)NNODES * HID);
    int*   starts    = csr_row + NEDGES;
    int*   counts    = starts + NNODES + 1;
    int*   cursor    = counts + NNODES;
    int*   blocksums = cursor + NNODES;
    int*   blockoffs = blocksums + 256;
    short* wencT     = (short*)(blockoffs + 256);

    hipMemsetAsync(counts, 0, (size_t)NNODES * sizeof(int), stream);
    prep_weights<<<(2 * INSZ * HID + 255) / 256, 256, 0, stream>>>(W_enc, W_dec, wencT, wdecT);
    count_kernel<<<(NEDGES + 255) / 256, 256, 0, stream>>>(ecol, counts);
    partial_kernel<<<NBLK, 256, 0, stream>>>(counts, blocksums);
    scan_blocks<<<1, 256, 0, stream>>>(blocksums, blockoffs);
    scan_final<<<NBLK, 256, 0, stream>>>(counts, blockoffs, starts, cursor, dinv);
    scatter_kernel<<<(NEDGES + 255) / 256, 256, 0, stream>>>(erow, ecol, cursor, csr_row);
    encoder_mfma<<<(NNODES + 63) / 64, 256, 0, stream>>>(x, wencT, b_enc, h);
    aggregate_csr_kernel<<<((size_t)NNODES * 32 + 255) / 256, 256, 0, stream>>>(starts, csr_row, dinv, h, agg);
    decoder_mfma<<<(NNODES + 63) / 64, 512, 0, stream>>>(agg, gcn_bias, wdecT, b_dec, out);
}